// Round 5
// baseline (217211.719 us; speedup 1.0000x reference)
//
#include <hip/hip_runtime.h>

typedef unsigned short u16;
typedef unsigned int u32;
typedef __attribute__((ext_vector_type(8))) short bf16x8;
typedef __attribute__((ext_vector_type(4))) float f32x4;

#define TOUT 500
#define KATT 1792
#define KDEC 2560

// ---------------- workspace layout (bytes) ----------------
constexpr size_t OW_ATT = 0;                                   // bf16 [4096][1792]
constexpr size_t OW_DEC = OW_ATT + (size_t)4096*KATT*2;        // bf16 [4096][2560]
constexpr size_t OMEMB  = OW_DEC + (size_t)4096*KDEC*2;        // bf16 [16384][512] memory
constexpr size_t OPMB   = OMEMB + (size_t)32*512*512*2;        // bf16 [16384][128] pm
constexpr size_t OPREB  = OPMB + (size_t)32*512*128*2;         // bf16 [500*32][256]
constexpr size_t OWMB   = OPREB + (size_t)500*32*256*2;        // bf16 [128][512]
constexpr size_t OW1B   = OWMB + (size_t)128*512*2;            // bf16 [256][96]
constexpr size_t OW2B   = OW1B + (size_t)256*96*2;             // bf16 [256][256]
constexpr size_t OAXB   = OW2B + (size_t)256*256*2;            // bf16 [16000][96]
constexpr size_t OH1B   = OAXB + (size_t)16000*96*2;           // bf16 [16000][256]
constexpr size_t OBLOC  = OH1B + (size_t)16000*256*2;          // bf16 [128][64]
constexpr size_t OPGW   = OBLOC + (size_t)128*64*2;            // bf16 [96][1536]
constexpr size_t OWQB   = OPGW + (size_t)96*1536*2;            // bf16 [128][1024]
constexpr size_t OABIAS = OWQB + (size_t)128*1024*2;           // f32 [4096] combined att bias
constexpr size_t ODBIAS = OABIAS + 4096*4;                     // f32 [4096] combined dec bias
constexpr size_t OAATT  = ODBIAS + 4096*4;                     // bf16 [32][1792] (pre|actx|ah)
constexpr size_t OADEC  = OAATT + (size_t)32*KATT*2;           // bf16 [32][2560] (ah|actx|dh)
constexpr size_t OACTX  = OADEC + (size_t)32*KDEC*2;           // bf16 [2][32][512]
constexpr size_t OALOC  = OACTX + (size_t)2*32*512*2;          // bf16 [16384][64]
constexpr size_t OLOCB  = OALOC + (size_t)16384*64*2;          // bf16 [16384][128]
constexpr size_t OGATT  = OLOCB + (size_t)16384*128*2;         // f32 [32][4096]
constexpr size_t OGDEC  = OGATT + (size_t)32*4096*4;           // f32 [32][4096]
constexpr size_t OAC    = OGDEC + (size_t)32*4096*4;           // f32 [32][1024]
constexpr size_t OBAR   = OAC + (size_t)32*1024*4;             // u32 [2] grid barrier (zeroed)
constexpr size_t OEND   = OBAR + 1024;

#define DI __device__ __forceinline__

DI float bf2f(u16 u){ union {float f; u32 i;} x; x.i = ((u32)u)<<16; return x.f; }
DI u16 f2bf(float f){ union {float f; u32 i;} x; x.f = f; u32 r = x.i + 0x7FFFu + ((x.i>>16)&1u); return (u16)(r>>16); }
DI float sigm(float x){ return 1.f/(1.f+__expf(-x)); }
DI float tanhx(float x){ float e = __expf(2.f*x); return 1.f - 2.f/(e+1.f); }

// ---- hand-rolled grid barrier (counter+generation, agent scope) ----
// Same protocol ROCm's grid.sync() uses; we regular-launch 256 blocks at
// 1 block/CU on 256 CUs so all are co-resident. Bounded spin: a residency
// failure produces wrong output (diagnosable) instead of a hang.
DI void gbar(u32* bar, int tid){
  __syncthreads();                       // all waves drained (vmcnt(0) before s_barrier)
  if (tid == 0) {
    __threadfence();                     // agent release: wb dirty L2 to coherence point
    u32 g = __hip_atomic_load(bar+1, __ATOMIC_RELAXED, __HIP_MEMORY_SCOPE_AGENT);
    u32 a = __hip_atomic_fetch_add(bar+0, 1u, __ATOMIC_ACQ_REL, __HIP_MEMORY_SCOPE_AGENT);
    if (a == 255u) {
      __hip_atomic_store(bar+0, 0u, __ATOMIC_RELAXED, __HIP_MEMORY_SCOPE_AGENT);
      __hip_atomic_fetch_add(bar+1, 1u, __ATOMIC_RELEASE, __HIP_MEMORY_SCOPE_AGENT);
    } else {
      long spins = 0;
      while (__hip_atomic_load(bar+1, __ATOMIC_ACQUIRE, __HIP_MEMORY_SCOPE_AGENT) == g) {
        __builtin_amdgcn_s_sleep(8);
        if (++spins > 2000000L) break;   // safety valve: fail loud, not hung
      }
    }
    __threadfence();                     // agent acquire: inv L1/L2 before phase reads
  }
  __syncthreads();
}

// ---------------- prep kernels ----------------
__global__ void k_build_watt(char* ws, const float* wih, const float* whh){
  u16* W = (u16*)(ws + OW_ATT);
  int n = blockIdx.x;
  for (int k = threadIdx.x; k < KATT; k += 256) {
    float v = (k < 768) ? wih[(size_t)n*768 + k] : whh[(size_t)n*1024 + (k-768)];
    W[(size_t)n*KATT + k] = f2bf(v);
  }
}
__global__ void k_build_wdec(char* ws, const float* wih, const float* whh){
  u16* W = (u16*)(ws + OW_DEC);
  int n = blockIdx.x;
  for (int k = threadIdx.x; k < KDEC; k += 256) {
    float v = (k < 1536) ? wih[(size_t)n*1536 + k] : whh[(size_t)n*1024 + (k-1536)];
    W[(size_t)n*KDEC + k] = f2bf(v);
  }
}
__global__ void k_cvt(u16* dst, const float* src, long n){
  for (long i = (long)blockIdx.x*256 + threadIdx.x; i < n; i += (long)gridDim.x*256)
    dst[i] = f2bf(src[i]);
}
__global__ void k_build_w1(char* ws, const float* w1){
  u16* W = (u16*)(ws + OW1B);
  int n = blockIdx.x; int k = threadIdx.x;
  if (k < 96) W[n*96 + k] = f2bf(k < 80 ? w1[n*80 + k] : 0.f);
}
__global__ void k_build_pgw(char* ws, const float* pw, const float* gw){
  u16* W = (u16*)(ws + OPGW);
  int n = blockIdx.x;
  for (int k = threadIdx.x; k < 1536; k += 256) {
    float v = 0.f;
    if (n < 80) v = pw[(size_t)n*1536 + k];
    else if (n == 80) v = gw[k];
    W[(size_t)n*1536 + k] = f2bf(v);
  }
}
__global__ void k_build_ax(char* ws, const float* mels){
  u16* AX = (u16*)(ws + OAXB);
  long ntot = 16000L*96;
  for (long i = (long)blockIdx.x*256 + threadIdx.x; i < ntot; i += (long)gridDim.x*256) {
    int r = (int)(i/96), k = (int)(i%96);
    int tt = r >> 5, b = r & 31;
    float v = 0.f;
    if (k < 80 && tt > 0) v = mels[((size_t)b*80 + k)*500 + (tt-1)];
    AX[i] = f2bf(v);
  }
}
__global__ void k_build_mk(char* ws, const float* ldw, const float* lcw){
  u16* Bl = (u16*)(ws + OBLOC);
  int i = blockIdx.x*256 + threadIdx.x;
  if (i < 128*64) {
    int a = i >> 6, k = i & 63;
    float s = 0.f;
    if (k < 62) {
      int c = k/31, dk = k%31;
      for (int f = 0; f < 32; ++f) s += ldw[a*32+f]*lcw[(f*2 + c)*31 + dk];
    }
    Bl[i] = f2bf(s);
  }
}
__global__ void k_addbias(char* ws, const float* aih, const float* ahh,
                          const float* dih, const float* dhh){
  int i = blockIdx.x*256 + threadIdx.x;
  if (i < 4096) {
    ((float*)(ws+OABIAS))[i] = aih[i]+ahh[i];
    ((float*)(ws+ODBIAS))[i] = dih[i]+dhh[i];
  }
}
DI f32x4 gemm_tile(const u16* A, int lda, const u16* Bw, int ldb,
                   int m0, int n0, int K, f32x4 acc) {
  int ln = threadIdx.x & 63;
  const u16* ap = A + (size_t)(m0 + (ln&15))*lda + 8*(ln>>4);
  const u16* bp = Bw + (size_t)(n0 + (ln&15))*ldb + 8*(ln>>4);
  for (int k = 0; k < K; k += 32) {
    bf16x8 av = *(const bf16x8*)(ap + k);
    bf16x8 bv = *(const bf16x8*)(bp + k);
    acc = __builtin_amdgcn_mfma_f32_16x16x32_bf16(av, bv, acc, 0, 0, 0);
  }
  return acc;
}
__global__ void k_gemm_pre(const u16* A, int lda, const u16* Bw, int ldb,
                           int NT, int K, u16* C, int ldc, int relu){
  int mt = blockIdx.x; int wv = threadIdx.x>>6, ln = threadIdx.x&63;
  for (int nt = wv; nt < NT; nt += 4) {
    f32x4 acc = {0.f,0.f,0.f,0.f};
    acc = gemm_tile(A, lda, Bw, ldb, mt*16, nt*16, K, acc);
    int r = mt*16 + ((ln>>4)<<2), c = nt*16 + (ln&15);
    #pragma unroll
    for (int i = 0; i < 4; ++i) {
      float v = acc[i];
      if (relu) v = fmaxf(v, 0.f);
      C[(size_t)(r+i)*ldc + c] = f2bf(v);
    }
  }
}
__global__ void k_zero(char* ws){
  size_t n = (OEND - OAATT)/16;
  uint4* p = (uint4*)(ws + OAATT);
  uint4 z; z.x=0; z.y=0; z.z=0; z.w=0;
  for (size_t i = (size_t)blockIdx.x*256 + threadIdx.x; i < n; i += (size_t)gridDim.x*256) p[i] = z;
}
__global__ void k_pre0(char* ws){
  u16* AATT = (u16*)(ws+OAATT);
  const u16* PREB = (const u16*)(ws+OPREB);
  int b = blockIdx.x;
  AATT[(size_t)b*KATT + threadIdx.x] = PREB[(size_t)b*256 + threadIdx.x];
}

// ---------------- main persistent kernel (regular launch + custom barrier) ----------------
// LDS 112KB: W_att n-tile 56KB (swizzled) + W_dec n-tile k in [1024,2560) 48KB
// (swizzled) + 8KB scratch. W_dec k in [0,1024) streams from global (L3-backed).
// Loc-conv merged kernel lives in 64 VGPRs.
__global__ void __launch_bounds__(256, 1)
k_main(char* ws, const float* vv, const float* pb, const float* gb, float* out)
{
  constexpr int LA_ATT = 0;          // 16 rows * 3584 B = 57344
  constexpr int LA_DEC = 57344;      // 16 rows * 3072 B = 49152
  constexpr int LA_SCR = 106496;     // 8192 B scratch
  __shared__ __align__(16) char LDSM[114688];

  const u16* WATT = (const u16*)(ws + OW_ATT);
  const u16* WDEC = (const u16*)(ws + OW_DEC);
  const u16* MEMB = (const u16*)(ws + OMEMB);
  const u16* PMB  = (const u16*)(ws + OPMB);
  const u16* PREB = (const u16*)(ws + OPREB);
  const u16* BLOCW= (const u16*)(ws + OBLOC);
  const u16* PGW  = (const u16*)(ws + OPGW);
  const u16* WQB  = (const u16*)(ws + OWQB);
  const float* ABIAS = (const float*)(ws + OABIAS);
  const float* DBIAS = (const float*)(ws + ODBIAS);
  u16* AATT = (u16*)(ws + OAATT);
  u16* ADEC = (u16*)(ws + OADEC);
  u16* ACTX = (u16*)(ws + OACTX);
  u16* ALOC = (u16*)(ws + OALOC);
  u16* LOCB = (u16*)(ws + OLOCB);
  float* GATT = (float*)(ws + OGATT);
  float* GDEC = (float*)(ws + OGDEC);
  float* AC   = (float*)(ws + OAC);
  u32* BAR    = (u32*)(ws + OBAR);
  float* out_mel  = out;
  float* out_gate = out + 1280000;
  float* out_aln  = out + 1296000;

  const int bid = blockIdx.x, tid = threadIdx.x;
  const int wv = tid>>6, ln = tid&63;

  // ---- loc-conv merged kernel B-fragments -> registers (held across t-loop) ----
  bf16x8 locB0[8], locB1[8];
  {
    const u16* base = BLOCW + (size_t)(ln&15)*64 + 8*(ln>>4);
    #pragma unroll
    for (int nt = 0; nt < 8; ++nt) {
      locB0[nt] = *(const bf16x8*)(base + nt*16*64);
      locB1[nt] = *(const bf16x8*)(base + nt*16*64 + 32);
    }
  }
  // ---- one-time LDS weight staging (16B units, XOR-swizzled per row) ----
  {
    const u16* s = WATT + (size_t)bid*16*KATT;
    for (int idx = tid; idx < 16*224; idx += 256) {
      int r = idx/224, u = idx - r*224;
      *(uint4*)(LDSM + LA_ATT + r*3584 + ((u^(r&7))<<4)) = *(const uint4*)(s + (size_t)r*KATT + u*8);
    }
    const u16* s2 = WDEC + (size_t)bid*16*KDEC + 1024;   // k in [1024,2560)
    for (int idx = tid; idx < 16*192; idx += 256) {
      int r = idx/192, u = idx - r*192;
      *(uint4*)(LDSM + LA_DEC + r*3072 + ((u^(r&7))<<4)) = *(const uint4*)(s2 + (size_t)r*KDEC + u*8);
    }
  }
  if (bid < 32)       { float* sAWC = (float*)(LDSM+LA_SCR+2048); for (int i=tid;i<512;i+=256) sAWC[i]=0.f; }
  else if (bid < 64)  { float* sDC  = (float*)(LDSM+LA_SCR+3072); for (int i=tid;i<1024;i+=256) sDC[i]=0.f; }
  __syncthreads();

  for (int t = 0; t <= TOUT; ++t) {
    // ================= phase G : GEMMs =================
    if (wv < 2) {
      if (t < TOUT) {
        { // attention-LSTM gates, step t; m-tile = wv, n-tile = bid (B from LDS)
          const u16* ap = AATT + (size_t)(wv*16 + (ln&15))*KATT + 8*(ln>>4);
          const char* bb = LDSM + LA_ATT + (ln&15)*3584;
          const int swz = ln&7;
          f32x4 acc = {0.f,0.f,0.f,0.f};
          #pragma unroll 8
          for (int i = 0; i < 56; ++i) {
            bf16x8 av = *(const bf16x8*)(ap + i*32);
            bf16x8 bv = *(const bf16x8*)(bb + (((i*4 + (ln>>4)) ^ swz)<<4));
            acc = __builtin_amdgcn_mfma_f32_16x16x32_bf16(av, bv, acc, 0,0,0);
          }
          int r = wv*16 + ((ln>>4)<<2), c = bid*16 + (ln&15);
          #pragma unroll
          for (int i2 = 0; i2 < 4; ++i2) GATT[(size_t)(r+i2)*4096 + c] = acc[i2];
        }
        // merged location conv+dense GEMM (2 m-tiles per wave, B in registers)
        #pragma unroll
        for (int rep = 0; rep < 2; ++rep) {
          int q = bid*4 + wv*2 + rep;
          const u16* ar = ALOC + (size_t)(q*16 + (ln&15))*64 + 8*(ln>>4);
          bf16x8 a0 = *(const bf16x8*)(ar);
          bf16x8 a1 = *(const bf16x8*)(ar + 32);
          int rr = q*16 + ((ln>>4)<<2);
          #pragma unroll
          for (int nt = 0; nt < 8; ++nt) {
            f32x4 a2 = {0.f,0.f,0.f,0.f};
            a2 = __builtin_amdgcn_mfma_f32_16x16x32_bf16(a0, locB0[nt], a2, 0,0,0);
            a2 = __builtin_amdgcn_mfma_f32_16x16x32_bf16(a1, locB1[nt], a2, 0,0,0);
            int cc = nt*16 + (ln&15);
            #pragma unroll
            for (int i2=0;i2<4;++i2) LOCB[(size_t)(rr+i2)*128 + cc] = f2bf(a2[i2]);
          }
        }
      }
    } else {
      if (t >= 1) { // decoder-LSTM gates, step t-1; B: k<1024 global, k>=1024 LDS
        int m = wv-2;
        const u16* ap = ADEC + (size_t)(m*16 + (ln&15))*KDEC + 8*(ln>>4);
        f32x4 acc = {0.f,0.f,0.f,0.f};
        {
          const u16* bp = WDEC + (size_t)(bid*16 + (ln&15))*KDEC + 8*(ln>>4);
          #pragma unroll 8
          for (int i = 0; i < 32; ++i) {
            bf16x8 av = *(const bf16x8*)(ap + i*32);
            bf16x8 bv = *(const bf16x8*)(bp + i*32);
            acc = __builtin_amdgcn_mfma_f32_16x16x32_bf16(av, bv, acc, 0,0,0);
          }
        }
        {
          const char* bb = LDSM + LA_DEC + (ln&15)*3072;
          const int swz = ln&7;
          #pragma unroll 8
          for (int i = 0; i < 48; ++i) {
            bf16x8 av = *(const bf16x8*)(ap + 1024 + i*32);
            bf16x8 bv = *(const bf16x8*)(bb + (((i*4 + (ln>>4)) ^ swz)<<4));
            acc = __builtin_amdgcn_mfma_f32_16x16x32_bf16(av, bv, acc, 0,0,0);
          }
        }
        int r = m*16 + ((ln>>4)<<2), c = bid*16 + (ln&15);
        #pragma unroll
        for (int i2 = 0; i2 < 4; ++i2) GDEC[(size_t)(r+i2)*4096 + c] = acc[i2];
      }
    }
    gbar(BAR, tid);
    // ================= phase A =================
    if (bid < 32) {
      if (t < TOUT) {
        const int b = bid;
        float* sE   = (float*)(LDSM+LA_SCR);            // aw (f32[512])
        float* sAWC = (float*)(LDSM+LA_SCR+2048);       // cumulative aw (persistent)
        u16*   sAH  = (u16*)(LDSM+LA_SCR+4096);         // ah bf16[1024]
        float* sPQ  = (float*)(LDSM+LA_SCR+4096+2048);  // f32[128]
        float* sRED = (float*)(LDSM+LA_SCR+4096+2560);  // f32[32]
        float* sVV  = (float*)(LDSM+LA_SCR+4096+2816);  // f32[128]
        u16*   sCP  = (u16*)(LDSM+LA_SCR+4096);         // context partials (aliases sAH..)
        if (tid < 32) *(f32x4*)(sVV + tid*4) = *(const f32x4*)(vv + tid*4);
        // attention LSTM pointwise
        {
          int u0 = tid*4;
          const float* gr = GATT + (size_t)b*4096;
          f32x4 xi = *(const f32x4*)(gr + u0);        xi += *(const f32x4*)(ABIAS + u0);
          f32x4 xf = *(const f32x4*)(gr + 1024 + u0); xf += *(const f32x4*)(ABIAS + 1024 + u0);
          f32x4 xg = *(const f32x4*)(gr + 2048 + u0); xg += *(const f32x4*)(ABIAS + 2048 + u0);
          f32x4 xo = *(const f32x4*)(gr + 3072 + u0); xo += *(const f32x4*)(ABIAS + 3072 + u0);
          f32x4 c0 = *(f32x4*)(AC + b*1024 + u0);
          u16 hb[4];
          #pragma unroll
          for (int j=0;j<4;++j){
            float c2 = sigm(xf[j])*c0[j] + sigm(xi[j])*tanhx(xg[j]);
            float h2 = sigm(xo[j])*tanhx(c2);
            c0[j]=c2; hb[j]=f2bf(h2); sAH[u0+j]=hb[j];
          }
          *(f32x4*)(AC + b*1024 + u0) = c0;
          uint2 hp = *(uint2*)hb;
          *(uint2*)(AATT + (size_t)b*KATT + 768 + u0) = hp;
          *(uint2*)(ADEC + (size_t)b*KDEC + u0) = hp;
        }
        __syncthreads();
        // pq = ah . wq^T
        {
          int a = tid>>1, half = tid&1;
          const u16* wr = WQB + (size_t)a*1024 + half*512;
          const u16* hr = sAH + half*512;
          float a0=0,a1=0,a2=0,a3=0;
          #pragma unroll 8
          for (int j = 0; j < 64; ++j) {
            bf16x8 w8 = *(const bf16x8*)(wr + j*8);
            bf16x8 h8 = *(const bf16x8*)(hr + j*8);
            float s = 0.f;
            #pragma unroll
            for (int e=0;e<8;++e) s += bf2f((u16)w8[e])*bf2f((u16)h8[e]);
            if ((j&3)==0) a0+=s; else if((j&3)==1) a1+=s; else if((j&3)==2) a2+=s; else a3+=s;
          }
          float s = (a0+a1)+(a2+a3);
          s += __shfl_xor(s, 1);
          if (half==0) sPQ[a] = s;
        }
        __syncthreads();
        // energies (kept in registers)
        float e0r=0.f, e1r=0.f;
        #pragma unroll
        for (int pass=0; pass<2; ++pass) {
          int tt = tid + pass*256;
          const u16* pmr = PMB  + ((size_t)b*512 + tt)*128;
          const u16* lor = LOCB + ((size_t)b*512 + tt)*128;
          float s = 0.f;
          #pragma unroll 4
          for (int j = 0; j < 16; ++j) {
            bf16x8 pm8 = *(const bf16x8*)(pmr + j*8);
            bf16x8 lo8 = *(const bf16x8*)(lor + j*8);
            f32x4 q0 = *(const f32x4*)(sPQ + j*8), q1 = *(const f32x4*)(sPQ + j*8 + 4);
            f32x4 v0 = *(const f32x4*)(sVV + j*8), v1 = *(const f32x4*)(sVV + j*8 + 4);
            #pragma unroll
            for (int e=0;e<4;++e) s += v0[e]*tanhx(q0[e] + bf2f((u16)pm8[e])   + bf2f((u16)lo8[e]));
            #pragma unroll
            for (int e=0;e<4;++e) s += v1[e]*tanhx(q1[e] + bf2f((u16)pm8[4+e]) + bf2f((u16)lo8[4+e]));
          }
          if (pass==0) e0r=s; else e1r=s;
        }
        // softmax (wave shuffles + tiny LDS cross-wave)
        {
          float m = fmaxf(e0r,e1r);
          #pragma unroll
          for (int o=32;o>0;o>>=1) m = fmaxf(m, __shfl_xor(m,o));
          if (ln==0) sRED[wv] = m;
          __syncthreads();
          m = fmaxf(fmaxf(sRED[0],sRED[1]), fmaxf(sRED[2],sRED[3]));
          float x0 = __expf(e0r-m), x1 = __expf(e1r-m);
          float sm = x0+x1;
          #pragma unroll
          for (int o=32;o>0;o>>=1) sm += __shfl_xor(sm,o);
          if (ln==0) sRED[8+wv] = sm;
          __syncthreads();
          sm = (sRED[8]+sRED[9])+(sRED[10]+sRED[11]);
          float inv = 1.f/sm;
          float w0 = x0*inv, w1 = x1*inv;
          sE[tid] = w0; sE[tid+256] = w1;
          sAWC[tid] += w0; sAWC[tid+256] += w1;
          out_aln[((size_t)b*500 + t)*512 + tid] = w0;
          out_aln[((size_t)b*500 + t)*512 + 256 + tid] = w1;
        }
        __syncthreads();
        // context: coalesced bf16x8 loads, per-wave partials -> LDS bf16
        {
          const u16* mb = MEMB + (size_t)b*512*512 + ln*8;
          float a8[8];
          #pragma unroll
          for (int e=0;e<8;++e) a8[e]=0.f;
          #pragma unroll 4
          for (int tt = wv; tt < 512; tt += 4) {
            float aw = sE[tt];
            bf16x8 m8 = *(const bf16x8*)(mb + (size_t)tt*512);
            #pragma unroll
            for (int e=0;e<8;++e) a8[e] += aw*bf2f((u16)m8[e]);
          }
          u16 pk[8];
          #pragma unroll
          for (int e=0;e<8;++e) pk[e] = f2bf(a8[e]);
          *(uint4*)(sCP + wv*512 + ln*8) = *(uint4*)pk;
        }
        __syncthreads();
        {
          int e2 = tid*2;
          float c0=0.f,c1=0.f;
          #pragma unroll
          for (int g=0; g<4; ++g) {
            u32 two = *(const u32*)(sCP + g*512 + e2);
            c0 += bf2f((u16)(two&0xffffu));
            c1 += bf2f((u16)(two>>16));
          }
          u32 packed = (u32)f2bf(c0) | ((u32)f2bf(c1)<<16);
          *(u32*)(AATT + (size_t)b*KATT + 256 + e2) = packed;
          *(u32*)(ADEC + (size_t)b*KDEC + 1024 + e2) = packed;
          *(u32*)(ACTX + (size_t)(t&1)*16384 + b*512 + e2) = packed;
        }
        // build ALOC rows for step t+1 from sE/sAWC
        #pragma unroll
        for (int rep=0; rep<2; ++rep) {
          int tt = tid + rep*256;
          u16* dst = ALOC + ((size_t)b*512 + tt)*64;
          #pragma unroll
          for (int k8=0;k8<8;++k8){
            u16 buf[8];
            #pragma unroll
            for (int j=0;j<8;++j){
              int k = k8*8+j;
              float v = 0.f;
              if (k < 31)      { int ts = tt + k - 15; if (ts>=0 && ts<512) v = sE[ts]; }
              else if (k < 62) { int ts = tt + k - 46; if (ts>=0 && ts<512) v = sAWC[ts]; }
              buf[j] = f2bf(v);
            }
            *(uint4*)(dst + k8*8) = *(uint4*)buf;
          }
        }
        // prenet frame for t+1
        if (t+1 < TOUT && tid < 32) {
          *(uint4*)(AATT + (size_t)b*KATT + tid*8) =
            *(const uint4*)(PREB + ((size_t)(t+1)*32 + b)*256 + tid*8);
        }
      }
    } else if (bid < 64) {
      if (t >= 1) {
        const int b = bid - 32;
        u16*   sDHA = (u16*)(LDSM+LA_SCR);        // bf16[1536] (dh|actx)
        float* sDC  = (float*)(LDSM+LA_SCR+3072); // f32[1024] cell state (persistent)
        {
          int u0 = tid*4;
          const float* gr = GDEC + (size_t)b*4096;
          f32x4 xi = *(const f32x4*)(gr + u0);        xi += *(const f32x4*)(DBIAS + u0);
          f32x4 xf = *(const f32x4*)(gr + 1024 + u0); xf += *(const f32x4*)(DBIAS + 1024 + u0);
          f32x4 xg = *(const f32x4*)(gr + 2048 + u0); xg += *(const f32x4*)(DBIAS + 2048 + u0);
          f32x4 xo = *(const f32x4*)(gr + 3072 + u0); xo += *(const f32x4*)(DBIAS + 3072 + u0);
          f32x4 c0 = *(f32x4*)(sDC + u0);
          u16 hb[4];
          #pragma unroll
          for (int j=0;j<4;++j){
            float c2 = sigm(xf[j])*c0[j] + sigm(xi[j])*tanhx(xg[j]);
            float h2 = sigm(xo[j])*tanhx(c2);
            c0[j]=c2; hb[j]=f2bf(h2); sDHA[u0+j]=hb[j];
          }
          *(f32x4*)(sDC + u0) = c0;
          *(uint2*)(ADEC + (size_t)b*KDEC + 1536 + u0) = *(uint2*)hb;
        }
        if (tid < 64) {
          *(uint4*)(sDHA + 1024 + tid*8) =
            *(const uint4*)(ACTX + (size_t)((t-1)&1)*16384 + b*512 + tid*8);
        }
        __syncthreads();
        // proj + gate for step t-1
        if (tid < 192) {
          int c = tid>>1, half = tid&1;
          const u16* wr = PGW + (size_t)c*1536 + half*768;
          const u16* hr = sDHA + half*768;
          float a0=0,a1=0,a2=0,a3=0;
          #pragma unroll 8
          for (int j = 0; j < 96; ++j) {
            bf16x8 w8 = *(const bf16x8*)(wr + j*8);
            bf16x8 h8 = *(const bf16x8*)(hr + j*8);
            float s = 0.f;
            #pragma unroll
            for (int e=0;e<8;++e) s += bf2f((u16)w8[e])*bf2f((u16)h8[e]);
            if ((j&3)==0) a0+=s; else if((j&3)==1) a1+=s; else if((j&3)==2) a2+=s; else a3+=s;
          }
          float s = (a0+a1)+(a2+a3);
          s += __shfl_xor(s, 1);
          if (half==0) {
            if (c < 80)      out_mel[((size_t)b*80 + c)*500 + (t-1)] = s + pb[c];
            else if (c==80)  out_gate[(size_t)b*500 + (t-1)] = s + gb[0];
          }
        }
      }
    }
    gbar(BAR, tid);
  }
}

// ---------------- host ----------------
extern "C" void kernel_launch(void* const* d_in, const int* in_sizes, int n_in,
                              void* d_out, int out_size, void* d_ws, size_t ws_size,
                              hipStream_t stream) {
  const float* memory = (const float*)d_in[0];
  const float* mels   = (const float*)d_in[1];
  const float* pw1    = (const float*)d_in[2];
  const float* pw2    = (const float*)d_in[3];
  const float* awih   = (const float*)d_in[4];
  const float* awhh   = (const float*)d_in[5];
  const float* abih   = (const float*)d_in[6];
  const float* abhh   = (const float*)d_in[7];
  const float* wq     = (const float*)d_in[8];
  const float* wm     = (const float*)d_in[9];
  const float* vv     = (const float*)d_in[10];
  const float* lcw    = (const float*)d_in[11];
  const float* ldw    = (const float*)d_in[12];
  const float* dwih   = (const float*)d_in[13];
  const float* dwhh   = (const float*)d_in[14];
  const float* dbih   = (const float*)d_in[15];
  const float* dbhh   = (const float*)d_in[16];
  const float* prw    = (const float*)d_in[17];
  const float* prb    = (const float*)d_in[18];
  const float* gw     = (const float*)d_in[19];
  const float* gb     = (const float*)d_in[20];
  char* ws = (char*)d_ws;
  float* outp = (float*)d_out;

  hipLaunchKernelGGL(k_build_watt, dim3(4096), dim3(256), 0, stream, ws, awih, awhh);
  hipLaunchKernelGGL(k_build_wdec, dim3(4096), dim3(256), 0, stream, ws, dwih, dwhh);
  hipLaunchKernelGGL(k_cvt, dim3(2048), dim3(256), 0, stream, (u16*)(ws+OMEMB), memory, (long)32*512*512);
  hipLaunchKernelGGL(k_cvt, dim3(256), dim3(256), 0, stream, (u16*)(ws+OWMB), wm, (long)128*512);
  hipLaunchKernelGGL(k_cvt, dim3(256), dim3(256), 0, stream, (u16*)(ws+OW2B), pw2, (long)256*256);
  hipLaunchKernelGGL(k_cvt, dim3(512), dim3(256), 0, stream, (u16*)(ws+OWQB), wq, (long)128*1024);
  hipLaunchKernelGGL(k_build_w1, dim3(256), dim3(128), 0, stream, ws, pw1);
  hipLaunchKernelGGL(k_build_pgw, dim3(96), dim3(256), 0, stream, ws, prw, gw);
  hipLaunchKernelGGL(k_build_ax, dim3(2048), dim3(256), 0, stream, ws, mels);
  hipLaunchKernelGGL(k_build_mk, dim3(32), dim3(256), 0, stream, ws, ldw, lcw);
  hipLaunchKernelGGL(k_addbias, dim3(16), dim3(256), 0, stream, ws, abih, abhh, dbih, dbhh);
  // pm = memory . wm^T   [16384 x 128], K=512
  hipLaunchKernelGGL(k_gemm_pre, dim3(1024), dim3(256), 0, stream,
    (const u16*)(ws+OMEMB), 512, (const u16*)(ws+OWMB), 512, 8, 512, (u16*)(ws+OPMB), 128, 0);
  // prenet layer 1: [16000 x 256], K=96
  hipLaunchKernelGGL(k_gemm_pre, dim3(1000), dim3(256), 0, stream,
    (const u16*)(ws+OAXB), 96, (const u16*)(ws+OW1B), 96, 16, 96, (u16*)(ws+OH1B), 256, 1);
  // prenet layer 2: [16000 x 256], K=256
  hipLaunchKernelGGL(k_gemm_pre, dim3(1000), dim3(256), 0, stream,
    (const u16*)(ws+OH1B), 256, (const u16*)(ws+OW2B), 256, 16, 256, (u16*)(ws+OPREB), 256, 1);
  hipLaunchKernelGGL(k_zero, dim3(2048), dim3(256), 0, stream, ws);
  hipLaunchKernelGGL(k_pre0, dim3(32), dim3(256), 0, stream, ws);

  // regular launch; co-residency is physical (256 blocks, 1/CU via 112KB LDS)
  hipLaunchKernelGGL(k_main, dim3(256), dim3(256), 0, stream, ws, vv, prb, gb, outp);
}

// Round 6
// 63415.356 us; speedup vs baseline: 3.4252x; 3.4252x over previous
//
#include <hip/hip_runtime.h>

typedef unsigned short u16;
typedef unsigned int u32;
typedef __attribute__((ext_vector_type(8))) short bf16x8;
typedef __attribute__((ext_vector_type(4))) float f32x4;

#define TOUT 500
#define KATT 1792
#define KDEC 2560

// ---------------- workspace layout (bytes) ----------------
constexpr size_t OW_ATT = 0;                                   // bf16 [4096][1792]
constexpr size_t OW_DEC = OW_ATT + (size_t)4096*KATT*2;        // bf16 [4096][2560]
constexpr size_t OMEMB  = OW_DEC + (size_t)4096*KDEC*2;        // bf16 [16384][512] memory
constexpr size_t OPMB   = OMEMB + (size_t)32*512*512*2;        // bf16 [16384][128] pm
constexpr size_t OPREB  = OPMB + (size_t)32*512*128*2;         // bf16 [500*32][256]
constexpr size_t OWMB   = OPREB + (size_t)500*32*256*2;        // bf16 [128][512]
constexpr size_t OW1B   = OWMB + (size_t)128*512*2;            // bf16 [256][96]
constexpr size_t OW2B   = OW1B + (size_t)256*96*2;             // bf16 [256][256]
constexpr size_t OAXB   = OW2B + (size_t)256*256*2;            // bf16 [16000][96]
constexpr size_t OH1B   = OAXB + (size_t)16000*96*2;           // bf16 [16000][256]
constexpr size_t OBLOC  = OH1B + (size_t)16000*256*2;          // bf16 [128][64]
constexpr size_t OPGW   = OBLOC + (size_t)128*64*2;            // bf16 [96][1536]
constexpr size_t OWQB   = OPGW + (size_t)96*1536*2;            // bf16 [128][1024]
constexpr size_t OABIAS = OWQB + (size_t)128*1024*2;           // f32 [4096] combined att bias
constexpr size_t ODBIAS = OABIAS + 4096*4;                     // f32 [4096] combined dec bias
constexpr size_t OAATT  = ODBIAS + 4096*4;                     // bf16 [32][1792] (pre|actx|ah)
constexpr size_t OADEC  = OAATT + (size_t)32*KATT*2;           // bf16 [32][2560] (ah|actx|dh)
constexpr size_t OACTX  = OADEC + (size_t)32*KDEC*2;           // bf16 [2][32][512]
constexpr size_t OALOC  = OACTX + (size_t)2*32*512*2;          // bf16 [16384][64]
constexpr size_t OLOCB  = OALOC + (size_t)16384*64*2;          // bf16 [16384][128]
constexpr size_t OGATT  = OLOCB + (size_t)16384*128*2;         // f32 [32][4096]
constexpr size_t OGDEC  = OGATT + (size_t)32*4096*4;           // f32 [32][4096]
constexpr size_t OAC    = OGDEC + (size_t)32*4096*4;           // f32 [32][1024]
constexpr size_t OBAR   = OAC + (size_t)32*1024*4;             // u32 [2] grid barrier (zeroed)
constexpr size_t OEND   = OBAR + 1024;

#define DI __device__ __forceinline__

DI float bf2f(u16 u){ union {float f; u32 i;} x; x.i = ((u32)u)<<16; return x.f; }
DI u16 f2bf(float f){ union {float f; u32 i;} x; x.f = f; u32 r = x.i + 0x7FFFu + ((x.i>>16)&1u); return (u16)(r>>16); }
DI float sigm(float x){ return 1.f/(1.f+__expf(-x)); }
DI float tanhx(float x){ float e = __expf(2.f*x); return 1.f - 2.f/(e+1.f); }

// ---- hand-rolled grid barrier (counter+generation, agent scope) ----
// R5 lesson: an ACQUIRE agent-scope load in the spin loop emits a per-XCD L2
// invalidate EVERY poll -> chipwide cache thrash (VALUBusy 0.8%, 68 GB/s).
// Correct protocol (what grid.sync does): RELAXED spin + one acquire fence on
// exit. Arrival RMW is ACQ_REL (release component writes back this block's
// plain stores); generation bump is RELEASE; exit __threadfence gives the
// acquire side via the fence-fence synchronization rule.
DI void gbar(u32* bar, int tid){
  __syncthreads();
  if (tid == 0) {
    u32 g = __hip_atomic_load(bar+1, __ATOMIC_RELAXED, __HIP_MEMORY_SCOPE_AGENT);
    u32 a = __hip_atomic_fetch_add(bar+0, 1u, __ATOMIC_ACQ_REL, __HIP_MEMORY_SCOPE_AGENT);
    if (a == 255u) {
      __hip_atomic_store(bar+0, 0u, __ATOMIC_RELAXED, __HIP_MEMORY_SCOPE_AGENT);
      __hip_atomic_fetch_add(bar+1, 1u, __ATOMIC_RELEASE, __HIP_MEMORY_SCOPE_AGENT);
    } else {
      long spins = 0;
      while (__hip_atomic_load(bar+1, __ATOMIC_RELAXED, __HIP_MEMORY_SCOPE_AGENT) == g) {
        __builtin_amdgcn_s_sleep(32);          // ~0.85us backoff per poll
        if (++spins > 2000000L) break;         // safety valve: fail loud, not hung
      }
    }
    __threadfence();                           // acquire side: inv stale caches once
  }
  __syncthreads();
}

// ---------------- prep kernels ----------------
__global__ void k_build_watt(char* ws, const float* wih, const float* whh){
  u16* W = (u16*)(ws + OW_ATT);
  int n = blockIdx.x;
  for (int k = threadIdx.x; k < KATT; k += 256) {
    float v = (k < 768) ? wih[(size_t)n*768 + k] : whh[(size_t)n*1024 + (k-768)];
    W[(size_t)n*KATT + k] = f2bf(v);
  }
}
__global__ void k_build_wdec(char* ws, const float* wih, const float* whh){
  u16* W = (u16*)(ws + OW_DEC);
  int n = blockIdx.x;
  for (int k = threadIdx.x; k < KDEC; k += 256) {
    float v = (k < 1536) ? wih[(size_t)n*1536 + k] : whh[(size_t)n*1024 + (k-1536)];
    W[(size_t)n*KDEC + k] = f2bf(v);
  }
}
__global__ void k_cvt(u16* dst, const float* src, long n){
  for (long i = (long)blockIdx.x*256 + threadIdx.x; i < n; i += (long)gridDim.x*256)
    dst[i] = f2bf(src[i]);
}
__global__ void k_build_w1(char* ws, const float* w1){
  u16* W = (u16*)(ws + OW1B);
  int n = blockIdx.x; int k = threadIdx.x;
  if (k < 96) W[n*96 + k] = f2bf(k < 80 ? w1[n*80 + k] : 0.f);
}
__global__ void k_build_pgw(char* ws, const float* pw, const float* gw){
  u16* W = (u16*)(ws + OPGW);
  int n = blockIdx.x;
  for (int k = threadIdx.x; k < 1536; k += 256) {
    float v = 0.f;
    if (n < 80) v = pw[(size_t)n*1536 + k];
    else if (n == 80) v = gw[k];
    W[(size_t)n*1536 + k] = f2bf(v);
  }
}
__global__ void k_build_ax(char* ws, const float* mels){
  u16* AX = (u16*)(ws + OAXB);
  long ntot = 16000L*96;
  for (long i = (long)blockIdx.x*256 + threadIdx.x; i < ntot; i += (long)gridDim.x*256) {
    int r = (int)(i/96), k = (int)(i%96);
    int tt = r >> 5, b = r & 31;
    float v = 0.f;
    if (k < 80 && tt > 0) v = mels[((size_t)b*80 + k)*500 + (tt-1)];
    AX[i] = f2bf(v);
  }
}
__global__ void k_build_mk(char* ws, const float* ldw, const float* lcw){
  u16* Bl = (u16*)(ws + OBLOC);
  int i = blockIdx.x*256 + threadIdx.x;
  if (i < 128*64) {
    int a = i >> 6, k = i & 63;
    float s = 0.f;
    if (k < 62) {
      int c = k/31, dk = k%31;
      for (int f = 0; f < 32; ++f) s += ldw[a*32+f]*lcw[(f*2 + c)*31 + dk];
    }
    Bl[i] = f2bf(s);
  }
}
__global__ void k_addbias(char* ws, const float* aih, const float* ahh,
                          const float* dih, const float* dhh){
  int i = blockIdx.x*256 + threadIdx.x;
  if (i < 4096) {
    ((float*)(ws+OABIAS))[i] = aih[i]+ahh[i];
    ((float*)(ws+ODBIAS))[i] = dih[i]+dhh[i];
  }
}
DI f32x4 gemm_tile(const u16* A, int lda, const u16* Bw, int ldb,
                   int m0, int n0, int K, f32x4 acc) {
  int ln = threadIdx.x & 63;
  const u16* ap = A + (size_t)(m0 + (ln&15))*lda + 8*(ln>>4);
  const u16* bp = Bw + (size_t)(n0 + (ln&15))*ldb + 8*(ln>>4);
  for (int k = 0; k < K; k += 32) {
    bf16x8 av = *(const bf16x8*)(ap + k);
    bf16x8 bv = *(const bf16x8*)(bp + k);
    acc = __builtin_amdgcn_mfma_f32_16x16x32_bf16(av, bv, acc, 0, 0, 0);
  }
  return acc;
}
__global__ void k_gemm_pre(const u16* A, int lda, const u16* Bw, int ldb,
                           int NT, int K, u16* C, int ldc, int relu){
  int mt = blockIdx.x; int wv = threadIdx.x>>6, ln = threadIdx.x&63;
  for (int nt = wv; nt < NT; nt += 4) {
    f32x4 acc = {0.f,0.f,0.f,0.f};
    acc = gemm_tile(A, lda, Bw, ldb, mt*16, nt*16, K, acc);
    int r = mt*16 + ((ln>>4)<<2), c = nt*16 + (ln&15);
    #pragma unroll
    for (int i = 0; i < 4; ++i) {
      float v = acc[i];
      if (relu) v = fmaxf(v, 0.f);
      C[(size_t)(r+i)*ldc + c] = f2bf(v);
    }
  }
}
__global__ void k_zero(char* ws){
  size_t n = (OEND - OAATT)/16;
  uint4* p = (uint4*)(ws + OAATT);
  uint4 z; z.x=0; z.y=0; z.z=0; z.w=0;
  for (size_t i = (size_t)blockIdx.x*256 + threadIdx.x; i < n; i += (size_t)gridDim.x*256) p[i] = z;
}
__global__ void k_pre0(char* ws){
  u16* AATT = (u16*)(ws+OAATT);
  const u16* PREB = (const u16*)(ws+OPREB);
  int b = blockIdx.x;
  AATT[(size_t)b*KATT + threadIdx.x] = PREB[(size_t)b*256 + threadIdx.x];
}

// ---------------- main persistent kernel (regular launch + custom barrier) ----------------
// LDS 112KB: W_att n-tile 56KB (swizzled) + W_dec n-tile k in [1024,2560) 48KB
// (swizzled) + 8KB scratch. W_dec k in [0,1024) streams from global (L3-backed).
// Loc-conv merged kernel lives in 64 VGPRs.
__global__ void __launch_bounds__(256, 1)
k_main(char* ws, const float* vv, const float* pb, const float* gb, float* out)
{
  constexpr int LA_ATT = 0;          // 16 rows * 3584 B = 57344
  constexpr int LA_DEC = 57344;      // 16 rows * 3072 B = 49152
  constexpr int LA_SCR = 106496;     // 8192 B scratch
  __shared__ __align__(16) char LDSM[114688];

  const u16* WATT = (const u16*)(ws + OW_ATT);
  const u16* WDEC = (const u16*)(ws + OW_DEC);
  const u16* MEMB = (const u16*)(ws + OMEMB);
  const u16* PMB  = (const u16*)(ws + OPMB);
  const u16* PREB = (const u16*)(ws + OPREB);
  const u16* BLOCW= (const u16*)(ws + OBLOC);
  const u16* PGW  = (const u16*)(ws + OPGW);
  const u16* WQB  = (const u16*)(ws + OWQB);
  const float* ABIAS = (const float*)(ws + OABIAS);
  const float* DBIAS = (const float*)(ws + ODBIAS);
  u16* AATT = (u16*)(ws + OAATT);
  u16* ADEC = (u16*)(ws + OADEC);
  u16* ACTX = (u16*)(ws + OACTX);
  u16* ALOC = (u16*)(ws + OALOC);
  u16* LOCB = (u16*)(ws + OLOCB);
  float* GATT = (float*)(ws + OGATT);
  float* GDEC = (float*)(ws + OGDEC);
  float* AC   = (float*)(ws + OAC);
  u32* BAR    = (u32*)(ws + OBAR);
  float* out_mel  = out;
  float* out_gate = out + 1280000;
  float* out_aln  = out + 1296000;

  const int bid = blockIdx.x, tid = threadIdx.x;
  const int wv = tid>>6, ln = tid&63;

  // ---- loc-conv merged kernel B-fragments -> registers (held across t-loop) ----
  bf16x8 locB0[8], locB1[8];
  {
    const u16* base = BLOCW + (size_t)(ln&15)*64 + 8*(ln>>4);
    #pragma unroll
    for (int nt = 0; nt < 8; ++nt) {
      locB0[nt] = *(const bf16x8*)(base + nt*16*64);
      locB1[nt] = *(const bf16x8*)(base + nt*16*64 + 32);
    }
  }
  // ---- one-time LDS weight staging (16B units, XOR-swizzled per row) ----
  {
    const u16* s = WATT + (size_t)bid*16*KATT;
    for (int idx = tid; idx < 16*224; idx += 256) {
      int r = idx/224, u = idx - r*224;
      *(uint4*)(LDSM + LA_ATT + r*3584 + ((u^(r&7))<<4)) = *(const uint4*)(s + (size_t)r*KATT + u*8);
    }
    const u16* s2 = WDEC + (size_t)bid*16*KDEC + 1024;   // k in [1024,2560)
    for (int idx = tid; idx < 16*192; idx += 256) {
      int r = idx/192, u = idx - r*192;
      *(uint4*)(LDSM + LA_DEC + r*3072 + ((u^(r&7))<<4)) = *(const uint4*)(s2 + (size_t)r*KDEC + u*8);
    }
  }
  if (bid < 32)       { float* sAWC = (float*)(LDSM+LA_SCR+2048); for (int i=tid;i<512;i+=256) sAWC[i]=0.f; }
  else if (bid < 64)  { float* sDC  = (float*)(LDSM+LA_SCR+3072); for (int i=tid;i<1024;i+=256) sDC[i]=0.f; }
  __syncthreads();

  for (int t = 0; t <= TOUT; ++t) {
    // ================= phase G : GEMMs =================
    if (wv < 2) {
      if (t < TOUT) {
        { // attention-LSTM gates, step t; m-tile = wv, n-tile = bid (B from LDS)
          const u16* ap = AATT + (size_t)(wv*16 + (ln&15))*KATT + 8*(ln>>4);
          const char* bb = LDSM + LA_ATT + (ln&15)*3584;
          const int swz = ln&7;
          f32x4 acc = {0.f,0.f,0.f,0.f};
          #pragma unroll 8
          for (int i = 0; i < 56; ++i) {
            bf16x8 av = *(const bf16x8*)(ap + i*32);
            bf16x8 bv = *(const bf16x8*)(bb + (((i*4 + (ln>>4)) ^ swz)<<4));
            acc = __builtin_amdgcn_mfma_f32_16x16x32_bf16(av, bv, acc, 0,0,0);
          }
          int r = wv*16 + ((ln>>4)<<2), c = bid*16 + (ln&15);
          #pragma unroll
          for (int i2 = 0; i2 < 4; ++i2) GATT[(size_t)(r+i2)*4096 + c] = acc[i2];
        }
        // merged location conv+dense GEMM (2 m-tiles per wave, B in registers)
        #pragma unroll
        for (int rep = 0; rep < 2; ++rep) {
          int q = bid*4 + wv*2 + rep;
          const u16* ar = ALOC + (size_t)(q*16 + (ln&15))*64 + 8*(ln>>4);
          bf16x8 a0 = *(const bf16x8*)(ar);
          bf16x8 a1 = *(const bf16x8*)(ar + 32);
          int rr = q*16 + ((ln>>4)<<2);
          #pragma unroll
          for (int nt = 0; nt < 8; ++nt) {
            f32x4 a2 = {0.f,0.f,0.f,0.f};
            a2 = __builtin_amdgcn_mfma_f32_16x16x32_bf16(a0, locB0[nt], a2, 0,0,0);
            a2 = __builtin_amdgcn_mfma_f32_16x16x32_bf16(a1, locB1[nt], a2, 0,0,0);
            int cc = nt*16 + (ln&15);
            #pragma unroll
            for (int i2=0;i2<4;++i2) LOCB[(size_t)(rr+i2)*128 + cc] = f2bf(a2[i2]);
          }
        }
      }
    } else {
      if (t >= 1) { // decoder-LSTM gates, step t-1; B: k<1024 global, k>=1024 LDS
        int m = wv-2;
        const u16* ap = ADEC + (size_t)(m*16 + (ln&15))*KDEC + 8*(ln>>4);
        f32x4 acc = {0.f,0.f,0.f,0.f};
        {
          const u16* bp = WDEC + (size_t)(bid*16 + (ln&15))*KDEC + 8*(ln>>4);
          #pragma unroll 8
          for (int i = 0; i < 32; ++i) {
            bf16x8 av = *(const bf16x8*)(ap + i*32);
            bf16x8 bv = *(const bf16x8*)(bp + i*32);
            acc = __builtin_amdgcn_mfma_f32_16x16x32_bf16(av, bv, acc, 0,0,0);
          }
        }
        {
          const char* bb = LDSM + LA_DEC + (ln&15)*3072;
          const int swz = ln&7;
          #pragma unroll 8
          for (int i = 0; i < 48; ++i) {
            bf16x8 av = *(const bf16x8*)(ap + 1024 + i*32);
            bf16x8 bv = *(const bf16x8*)(bb + (((i*4 + (ln>>4)) ^ swz)<<4));
            acc = __builtin_amdgcn_mfma_f32_16x16x32_bf16(av, bv, acc, 0,0,0);
          }
        }
        int r = m*16 + ((ln>>4)<<2), c = bid*16 + (ln&15);
        #pragma unroll
        for (int i2 = 0; i2 < 4; ++i2) GDEC[(size_t)(r+i2)*4096 + c] = acc[i2];
      }
    }
    gbar(BAR, tid);
    // ================= phase A =================
    if (bid < 32) {
      if (t < TOUT) {
        const int b = bid;
        float* sE   = (float*)(LDSM+LA_SCR);            // aw (f32[512])
        float* sAWC = (float*)(LDSM+LA_SCR+2048);       // cumulative aw (persistent)
        u16*   sAH  = (u16*)(LDSM+LA_SCR+4096);         // ah bf16[1024]
        float* sPQ  = (float*)(LDSM+LA_SCR+4096+2048);  // f32[128]
        float* sRED = (float*)(LDSM+LA_SCR+4096+2560);  // f32[32]
        float* sVV  = (float*)(LDSM+LA_SCR+4096+2816);  // f32[128]
        u16*   sCP  = (u16*)(LDSM+LA_SCR+4096);         // context partials (aliases sAH..)
        if (tid < 32) *(f32x4*)(sVV + tid*4) = *(const f32x4*)(vv + tid*4);
        // attention LSTM pointwise
        {
          int u0 = tid*4;
          const float* gr = GATT + (size_t)b*4096;
          f32x4 xi = *(const f32x4*)(gr + u0);        xi += *(const f32x4*)(ABIAS + u0);
          f32x4 xf = *(const f32x4*)(gr + 1024 + u0); xf += *(const f32x4*)(ABIAS + 1024 + u0);
          f32x4 xg = *(const f32x4*)(gr + 2048 + u0); xg += *(const f32x4*)(ABIAS + 2048 + u0);
          f32x4 xo = *(const f32x4*)(gr + 3072 + u0); xo += *(const f32x4*)(ABIAS + 3072 + u0);
          f32x4 c0 = *(f32x4*)(AC + b*1024 + u0);
          u16 hb[4];
          #pragma unroll
          for (int j=0;j<4;++j){
            float c2 = sigm(xf[j])*c0[j] + sigm(xi[j])*tanhx(xg[j]);
            float h2 = sigm(xo[j])*tanhx(c2);
            c0[j]=c2; hb[j]=f2bf(h2); sAH[u0+j]=hb[j];
          }
          *(f32x4*)(AC + b*1024 + u0) = c0;
          uint2 hp = *(uint2*)hb;
          *(uint2*)(AATT + (size_t)b*KATT + 768 + u0) = hp;
          *(uint2*)(ADEC + (size_t)b*KDEC + u0) = hp;
        }
        __syncthreads();
        // pq = ah . wq^T
        {
          int a = tid>>1, half = tid&1;
          const u16* wr = WQB + (size_t)a*1024 + half*512;
          const u16* hr = sAH + half*512;
          float a0=0,a1=0,a2=0,a3=0;
          #pragma unroll 8
          for (int j = 0; j < 64; ++j) {
            bf16x8 w8 = *(const bf16x8*)(wr + j*8);
            bf16x8 h8 = *(const bf16x8*)(hr + j*8);
            float s = 0.f;
            #pragma unroll
            for (int e=0;e<8;++e) s += bf2f((u16)w8[e])*bf2f((u16)h8[e]);
            if ((j&3)==0) a0+=s; else if((j&3)==1) a1+=s; else if((j&3)==2) a2+=s; else a3+=s;
          }
          float s = (a0+a1)+(a2+a3);
          s += __shfl_xor(s, 1);
          if (half==0) sPQ[a] = s;
        }
        __syncthreads();
        // energies (kept in registers)
        float e0r=0.f, e1r=0.f;
        #pragma unroll
        for (int pass=0; pass<2; ++pass) {
          int tt = tid + pass*256;
          const u16* pmr = PMB  + ((size_t)b*512 + tt)*128;
          const u16* lor = LOCB + ((size_t)b*512 + tt)*128;
          float s = 0.f;
          #pragma unroll 4
          for (int j = 0; j < 16; ++j) {
            bf16x8 pm8 = *(const bf16x8*)(pmr + j*8);
            bf16x8 lo8 = *(const bf16x8*)(lor + j*8);
            f32x4 q0 = *(const f32x4*)(sPQ + j*8), q1 = *(const f32x4*)(sPQ + j*8 + 4);
            f32x4 v0 = *(const f32x4*)(sVV + j*8), v1 = *(const f32x4*)(sVV + j*8 + 4);
            #pragma unroll
            for (int e=0;e<4;++e) s += v0[e]*tanhx(q0[e] + bf2f((u16)pm8[e])   + bf2f((u16)lo8[e]));
            #pragma unroll
            for (int e=0;e<4;++e) s += v1[e]*tanhx(q1[e] + bf2f((u16)pm8[4+e]) + bf2f((u16)lo8[4+e]));
          }
          if (pass==0) e0r=s; else e1r=s;
        }
        // softmax (wave shuffles + tiny LDS cross-wave)
        {
          float m = fmaxf(e0r,e1r);
          #pragma unroll
          for (int o=32;o>0;o>>=1) m = fmaxf(m, __shfl_xor(m,o));
          if (ln==0) sRED[wv] = m;
          __syncthreads();
          m = fmaxf(fmaxf(sRED[0],sRED[1]), fmaxf(sRED[2],sRED[3]));
          float x0 = __expf(e0r-m), x1 = __expf(e1r-m);
          float sm = x0+x1;
          #pragma unroll
          for (int o=32;o>0;o>>=1) sm += __shfl_xor(sm,o);
          if (ln==0) sRED[8+wv] = sm;
          __syncthreads();
          sm = (sRED[8]+sRED[9])+(sRED[10]+sRED[11]);
          float inv = 1.f/sm;
          float w0 = x0*inv, w1 = x1*inv;
          sE[tid] = w0; sE[tid+256] = w1;
          sAWC[tid] += w0; sAWC[tid+256] += w1;
          out_aln[((size_t)b*500 + t)*512 + tid] = w0;
          out_aln[((size_t)b*500 + t)*512 + 256 + tid] = w1;
        }
        __syncthreads();
        // context: coalesced bf16x8 loads, per-wave partials -> LDS bf16
        {
          const u16* mb = MEMB + (size_t)b*512*512 + ln*8;
          float a8[8];
          #pragma unroll
          for (int e=0;e<8;++e) a8[e]=0.f;
          #pragma unroll 4
          for (int tt = wv; tt < 512; tt += 4) {
            float aw = sE[tt];
            bf16x8 m8 = *(const bf16x8*)(mb + (size_t)tt*512);
            #pragma unroll
            for (int e=0;e<8;++e) a8[e] += aw*bf2f((u16)m8[e]);
          }
          u16 pk[8];
          #pragma unroll
          for (int e=0;e<8;++e) pk[e] = f2bf(a8[e]);
          *(uint4*)(sCP + wv*512 + ln*8) = *(uint4*)pk;
        }
        __syncthreads();
        {
          int e2 = tid*2;
          float c0=0.f,c1=0.f;
          #pragma unroll
          for (int g=0; g<4; ++g) {
            u32 two = *(const u32*)(sCP + g*512 + e2);
            c0 += bf2f((u16)(two&0xffffu));
            c1 += bf2f((u16)(two>>16));
          }
          u32 packed = (u32)f2bf(c0) | ((u32)f2bf(c1)<<16);
          *(u32*)(AATT + (size_t)b*KATT + 256 + e2) = packed;
          *(u32*)(ADEC + (size_t)b*KDEC + 1024 + e2) = packed;
          *(u32*)(ACTX + (size_t)(t&1)*16384 + b*512 + e2) = packed;
        }
        // build ALOC rows for step t+1 from sE/sAWC
        #pragma unroll
        for (int rep=0; rep<2; ++rep) {
          int tt = tid + rep*256;
          u16* dst = ALOC + ((size_t)b*512 + tt)*64;
          #pragma unroll
          for (int k8=0;k8<8;++k8){
            u16 buf[8];
            #pragma unroll
            for (int j=0;j<8;++j){
              int k = k8*8+j;
              float v = 0.f;
              if (k < 31)      { int ts = tt + k - 15; if (ts>=0 && ts<512) v = sE[ts]; }
              else if (k < 62) { int ts = tt + k - 46; if (ts>=0 && ts<512) v = sAWC[ts]; }
              buf[j] = f2bf(v);
            }
            *(uint4*)(dst + k8*8) = *(uint4*)buf;
          }
        }
        // prenet frame for t+1
        if (t+1 < TOUT && tid < 32) {
          *(uint4*)(AATT + (size_t)b*KATT + tid*8) =
            *(const uint4*)(PREB + ((size_t)(t+1)*32 + b)*256 + tid*8);
        }
      }
    } else if (bid < 64) {
      if (t >= 1) {
        const int b = bid - 32;
        u16*   sDHA = (u16*)(LDSM+LA_SCR);        // bf16[1536] (dh|actx)
        float* sDC  = (float*)(LDSM+LA_SCR+3072); // f32[1024] cell state (persistent)
        {
          int u0 = tid*4;
          const float* gr = GDEC + (size_t)b*4096;
          f32x4 xi = *(const f32x4*)(gr + u0);        xi += *(const f32x4*)(DBIAS + u0);
          f32x4 xf = *(const f32x4*)(gr + 1024 + u0); xf += *(const f32x4*)(DBIAS + 1024 + u0);
          f32x4 xg = *(const f32x4*)(gr + 2048 + u0); xg += *(const f32x4*)(DBIAS + 2048 + u0);
          f32x4 xo = *(const f32x4*)(gr + 3072 + u0); xo += *(const f32x4*)(DBIAS + 3072 + u0);
          f32x4 c0 = *(f32x4*)(sDC + u0);
          u16 hb[4];
          #pragma unroll
          for (int j=0;j<4;++j){
            float c2 = sigm(xf[j])*c0[j] + sigm(xi[j])*tanhx(xg[j]);
            float h2 = sigm(xo[j])*tanhx(c2);
            c0[j]=c2; hb[j]=f2bf(h2); sDHA[u0+j]=hb[j];
          }
          *(f32x4*)(sDC + u0) = c0;
          *(uint2*)(ADEC + (size_t)b*KDEC + 1536 + u0) = *(uint2*)hb;
        }
        if (tid < 64) {
          *(uint4*)(sDHA + 1024 + tid*8) =
            *(const uint4*)(ACTX + (size_t)((t-1)&1)*16384 + b*512 + tid*8);
        }
        __syncthreads();
        // proj + gate for step t-1
        if (tid < 192) {
          int c = tid>>1, half = tid&1;
          const u16* wr = PGW + (size_t)c*1536 + half*768;
          const u16* hr = sDHA + half*768;
          float a0=0,a1=0,a2=0,a3=0;
          #pragma unroll 8
          for (int j = 0; j < 96; ++j) {
            bf16x8 w8 = *(const bf16x8*)(wr + j*8);
            bf16x8 h8 = *(const bf16x8*)(hr + j*8);
            float s = 0.f;
            #pragma unroll
            for (int e=0;e<8;++e) s += bf2f((u16)w8[e])*bf2f((u16)h8[e]);
            if ((j&3)==0) a0+=s; else if((j&3)==1) a1+=s; else if((j&3)==2) a2+=s; else a3+=s;
          }
          float s = (a0+a1)+(a2+a3);
          s += __shfl_xor(s, 1);
          if (half==0) {
            if (c < 80)      out_mel[((size_t)b*80 + c)*500 + (t-1)] = s + pb[c];
            else if (c==80)  out_gate[(size_t)b*500 + (t-1)] = s + gb[0];
          }
        }
      }
    }
    gbar(BAR, tid);
  }
}

// ---------------- host ----------------
extern "C" void kernel_launch(void* const* d_in, const int* in_sizes, int n_in,
                              void* d_out, int out_size, void* d_ws, size_t ws_size,
                              hipStream_t stream) {
  const float* memory = (const float*)d_in[0];
  const float* mels   = (const float*)d_in[1];
  const float* pw1    = (const float*)d_in[2];
  const float* pw2    = (const float*)d_in[3];
  const float* awih   = (const float*)d_in[4];
  const float* awhh   = (const float*)d_in[5];
  const float* abih   = (const float*)d_in[6];
  const float* abhh   = (const float*)d_in[7];
  const float* wq     = (const float*)d_in[8];
  const float* wm     = (const float*)d_in[9];
  const float* vv     = (const float*)d_in[10];
  const float* lcw    = (const float*)d_in[11];
  const float* ldw    = (const float*)d_in[12];
  const float* dwih   = (const float*)d_in[13];
  const float* dwhh   = (const float*)d_in[14];
  const float* dbih   = (const float*)d_in[15];
  const float* dbhh   = (const float*)d_in[16];
  const float* prw    = (const float*)d_in[17];
  const float* prb    = (const float*)d_in[18];
  const float* gw     = (const float*)d_in[19];
  const float* gb     = (const float*)d_in[20];
  char* ws = (char*)d_ws;
  float* outp = (float*)d_out;

  hipLaunchKernelGGL(k_build_watt, dim3(4096), dim3(256), 0, stream, ws, awih, awhh);
  hipLaunchKernelGGL(k_build_wdec, dim3(4096), dim3(256), 0, stream, ws, dwih, dwhh);
  hipLaunchKernelGGL(k_cvt, dim3(2048), dim3(256), 0, stream, (u16*)(ws+OMEMB), memory, (long)32*512*512);
  hipLaunchKernelGGL(k_cvt, dim3(256), dim3(256), 0, stream, (u16*)(ws+OWMB), wm, (long)128*512);
  hipLaunchKernelGGL(k_cvt, dim3(256), dim3(256), 0, stream, (u16*)(ws+OW2B), pw2, (long)256*256);
  hipLaunchKernelGGL(k_cvt, dim3(512), dim3(256), 0, stream, (u16*)(ws+OWQB), wq, (long)128*1024);
  hipLaunchKernelGGL(k_build_w1, dim3(256), dim3(128), 0, stream, ws, pw1);
  hipLaunchKernelGGL(k_build_pgw, dim3(96), dim3(256), 0, stream, ws, prw, gw);
  hipLaunchKernelGGL(k_build_ax, dim3(2048), dim3(256), 0, stream, ws, mels);
  hipLaunchKernelGGL(k_build_mk, dim3(32), dim3(256), 0, stream, ws, ldw, lcw);
  hipLaunchKernelGGL(k_addbias, dim3(16), dim3(256), 0, stream, ws, abih, abhh, dbih, dbhh);
  // pm = memory . wm^T   [16384 x 128], K=512
  hipLaunchKernelGGL(k_gemm_pre, dim3(1024), dim3(256), 0, stream,
    (const u16*)(ws+OMEMB), 512, (const u16*)(ws+OWMB), 512, 8, 512, (u16*)(ws+OPMB), 128, 0);
  // prenet layer 1: [16000 x 256], K=96
  hipLaunchKernelGGL(k_gemm_pre, dim3(1000), dim3(256), 0, stream,
    (const u16*)(ws+OAXB), 96, (const u16*)(ws+OW1B), 96, 16, 96, (u16*)(ws+OH1B), 256, 1);
  // prenet layer 2: [16000 x 256], K=256
  hipLaunchKernelGGL(k_gemm_pre, dim3(1000), dim3(256), 0, stream,
    (const u16*)(ws+OH1B), 256, (const u16*)(ws+OW2B), 256, 16, 256, (u16*)(ws+OPREB), 256, 1);
  hipLaunchKernelGGL(k_zero, dim3(2048), dim3(256), 0, stream, ws);
  hipLaunchKernelGGL(k_pre0, dim3(32), dim3(256), 0, stream, ws);

  // regular launch; co-residency is physical (256 blocks, 1/CU via 112KB LDS)
  hipLaunchKernelGGL(k_main, dim3(256), dim3(256), 0, stream, ws, vv, prb, gb, outp);
}